// Round 3
// baseline (1100.559 us; speedup 1.0000x reference)
//
#include <hip/hip_runtime.h>
#include <stdint.h>

#define DD 160
#define HH 160
#define WW 160
#define NGRID (DD*HH*WW)
#define CIN 32
#define COUT 64
#define KK 27
#define BLOCK 1024
#define WPB 16           // waves per block
#define NSLICE 256       // voxel slices; grid = NSLICE*2 blocks (x2 cout halves)
#define PAIR 4096        // NSLICE*WPB : offset between the two voxels of a pair
#define STEP 8192        // 2*PAIR : per-wave voxel stride
#define M27 0x07FFFFFFu

typedef _Float16 h2_t __attribute__((ext_vector_type(2)));

__device__ __forceinline__ h2_t as_h2(uint32_t u) {
    union { uint32_t u; h2_t h; } c; c.u = u; return c.h;
}
__device__ __forceinline__ uint32_t f2h(float f) {
    union { _Float16 h; uint16_t u; } c; c.h = (_Float16)f; return (uint32_t)c.u;
}

// 2-wide f16 dot with f32 accumulate: v_dot2_f32_f16
__device__ __forceinline__ float dot2(uint32_t fu, uint32_t wu, float acc) {
#if defined(__has_builtin)
#if __has_builtin(__builtin_amdgcn_fdot2)
    return __builtin_amdgcn_fdot2(as_h2(fu), as_h2(wu), acc, false);
#else
    h2_t f = as_h2(fu), w = as_h2(wu);
    acc = fmaf((float)f.x, (float)w.x, acc);
    return fmaf((float)f.y, (float)w.y, acc);
#endif
#else
    h2_t f = as_h2(fu), w = as_h2(wu);
    acc = fmaf((float)f.x, (float)w.x, acc);
    return fmaf((float)f.y, (float)w.y, acc);
#endif
}

// fused prep: feats f32->f16 (+ zero row at index n), grid scatter, weight pack
__global__ void prep(const float4* __restrict__ f4, const int4* __restrict__ coors,
                     const float* __restrict__ w, uint2* __restrict__ fh,
                     int* __restrict__ grid, uint4* __restrict__ wpk, int n)
{
    int gid = blockIdx.x * 256 + threadIdx.x;
    const int nq = n * 8;                         // n*CIN/4 float4s == n*8 uint2 outputs
    if (gid < nq) {
        float4 v = f4[gid];
        uint2 r;
        r.x = f2h(v.x) | (f2h(v.y) << 16);
        r.y = f2h(v.z) | (f2h(v.w) << 16);
        fh[gid] = r;
    } else if (gid < nq + 8) {                    // zero feature row (index n)
        uint2 z; z.x = 0u; z.y = 0u;
        fh[gid] = z;
    } else if (gid < nq + 8 + n) {                // scatter voxel ids into dense grid
        int i = gid - (nq + 8);
        int4 c = coors[i];
        grid[(c.y*HH + c.z)*WW + c.w] = i;
    } else if (gid < nq + 8 + n + KK*4*COUT) {    // pack weights f32 -> f16 uint4 [k][g][co]
        int t = gid - (nq + 8 + n);
        int co = t & 63;
        int g  = (t >> 6) & 3;
        int k  = t >> 8;
        const float* base = w + (size_t)k*CIN*COUT + (size_t)(8*g)*COUT + co;
        uint4 r;
        r.x = f2h(base[0*COUT]) | (f2h(base[1*COUT]) << 16);
        r.y = f2h(base[2*COUT]) | (f2h(base[3*COUT]) << 16);
        r.z = f2h(base[4*COUT]) | (f2h(base[5*COUT]) << 16);
        r.w = f2h(base[6*COUT]) | (f2h(base[7*COUT]) << 16);
        wpk[t] = r;
    }
}

// resolve tap kk's source row for both voxels of the pair; invalid -> zero row (n)
#define RESOLVE(kk, JV) { \
    int iA_ = __builtin_amdgcn_readlane(nidx, (kk)); \
    int iB_ = __builtin_amdgcn_readlane(nidx, (kk) + 32); \
    iA_ = (iA_ < 0) ? n : iA_; \
    iB_ = (iB_ < 0) ? n : iB_; \
    JV = lolane ? iA_ : iB_; }

// load 4x uint4 (32 f16 feats = one row) from per-half-wave row JV
#define LOAD4(D0,D1,D2,D3,JV) { \
    const uint4* fp_ = fh4 + (size_t)(JV) * 4; \
    D0 = fp_[0]; D1 = fp_[1]; D2 = fp_[2]; D3 = fp_[3]; }

// 16 v_dot2_f32_f16 against this block's 32-cout LDS weight slice for tap kk
#define MAC4(F0,F1,F2,F3,kk) { \
    const uint4* wl_ = wlds + (size_t)(kk)*128 + co; \
    uint4 w0_ = wl_[0], w1_ = wl_[32], w2_ = wl_[64], w3_ = wl_[96]; \
    a0 = dot2(F0.x, w0_.x, a0); a1 = dot2(F0.y, w0_.y, a1); \
    a2 = dot2(F0.z, w0_.z, a2); a3 = dot2(F0.w, w0_.w, a3); \
    a0 = dot2(F1.x, w1_.x, a0); a1 = dot2(F1.y, w1_.y, a1); \
    a2 = dot2(F1.z, w1_.z, a2); a3 = dot2(F1.w, w1_.w, a3); \
    a0 = dot2(F2.x, w2_.x, a0); a1 = dot2(F2.y, w2_.y, a1); \
    a2 = dot2(F2.z, w2_.z, a2); a3 = dot2(F2.w, w2_.w, a3); \
    a0 = dot2(F3.x, w3_.x, a0); a1 = dot2(F3.y, w3_.y, a1); \
    a2 = dot2(F3.z, w3_.z, a2); a3 = dot2(F3.w, w3_.w, a3); }

// Each block owns 32 couts (h = bid&1) -> LDS 55,296 B -> 2 blocks/CU (32 waves).
// A wave computes a voxel PAIR simultaneously: lanes 0-31 = voxel A, 32-63 = voxel B,
// iterating the union tap mask; missing taps read the zero feature row.
__global__ __launch_bounds__(BLOCK, 8) void sparse_conv(
    const uint4* __restrict__ fh4, const int4* __restrict__ cc,
    const float* __restrict__ bias, const uint4* __restrict__ wpk,
    const int* __restrict__ grid, float* __restrict__ out, int n)
{
    __shared__ uint4 wlds[KK*4*32];   // 55,296 B

    const int h  = blockIdx.x & 1;
    const int sb = blockIdx.x >> 1;

    for (int t = threadIdx.x; t < KK*4*32; t += BLOCK) {
        int k = t >> 7, g = (t >> 5) & 3, c = t & 31;
        wlds[t] = wpk[(k*4 + g)*COUT + h*32 + c];
    }
    __syncthreads();

    const int lane = threadIdx.x & 63;
    const int wave = __builtin_amdgcn_readfirstlane((int)(threadIdx.x >> 6));
    const bool lolane = lane < 32;
    const int co = lane & 31;
    const float b = bias[h*32 + co];

    const int pl = co;
    const bool prober = pl < KK;
    const int dz = pl / 9 - 1;
    const int dy = (pl / 3) % 3 - 1;
    const int dx = pl % 3 - 1;
    const int hioff = lolane ? 0 : PAIR;

    int v = sb * WPB + wave;
    int nidx = -1;   // lanes 0..26 probe voxel v, lanes 32..58 probe v+PAIR

    auto probe = [&](int pb) -> int {
        int r = -1;
        int pv = pb + hioff;
        if (prober && pv < n) {
            int4 c = cc[pv];
            int nz = c.y + dz, ny = c.z + dy, nx = c.w + dx;
            if (nz >= 0 && nz < DD && ny >= 0 && ny < HH && nx >= 0 && nx < WW)
                r = grid[(nz*HH + ny)*WW + nx];
        }
        return r;
    };

    nidx = probe(v);

    while (v < n) {
        unsigned long long bal = __ballot(nidx >= 0);
        int nidx_next = probe(v + STEP);   // next pair's probe hides under MACs

        uint32_t mA = (uint32_t)bal & M27;
        uint32_t mB = (uint32_t)(bal >> 32) & M27;
        uint32_t m  = mA | mB;             // union; A's self bit guarantees m != 0

        float a0 = 0.f, a1 = 0.f, a2 = 0.f, a3 = 0.f;
        uint4 A0, A1, A2, A3, B0, B1, B2, B3;
        int jA, jB;
        int kA = __ffs(m) - 1; m &= m - 1;
        RESOLVE(kA, jA); LOAD4(A0, A1, A2, A3, jA);
        for (;;) {
            if (!m) { MAC4(A0, A1, A2, A3, kA); break; }
            int kB = __ffs(m) - 1; m &= m - 1;
            RESOLVE(kB, jB); LOAD4(B0, B1, B2, B3, jB);   // prefetch next tap
            MAC4(A0, A1, A2, A3, kA);
            if (!m) { MAC4(B0, B1, B2, B3, kB); break; }
            kA = __ffs(m) - 1; m &= m - 1;
            RESOLVE(kA, jA); LOAD4(A0, A1, A2, A3, jA);
            MAC4(B0, B1, B2, B3, kB);
        }

        float r = b + ((a0 + a1) + (a2 + a3));
        int vB = v + PAIR;
        int vo = lolane ? v : vB;
        if (lolane || vB < n)
            __builtin_nontemporal_store(r, out + (size_t)vo * COUT + h*32 + co);

        v += STEP;
        nidx = nidx_next;
    }
}

extern "C" void kernel_launch(void* const* d_in, const int* in_sizes, int n_in,
                              void* d_out, int out_size, void* d_ws, size_t ws_size,
                              hipStream_t stream) {
    const float* feats  = (const float*)d_in[0];
    const int*   coors  = (const int*)d_in[1];
    const float* weight = (const float*)d_in[2];
    const float* bias   = (const float*)d_in[3];
    float*       outp   = (float*)d_out;

    const int n = in_sizes[1] / 4;   // 400000

    int*   grid = (int*)d_ws;
    uint4* wpk  = (uint4*)((char*)d_ws + (size_t)NGRID * sizeof(int));
    uint2* fh   = (uint2*)((char*)d_ws + (size_t)NGRID * sizeof(int)
                           + (size_t)KK * 4 * COUT * sizeof(uint4));

    // dense index grid: fill with -1, then fused prep (convert + zero row + scatter + pack)
    hipMemsetAsync(grid, 0xFF, (size_t)NGRID * sizeof(int), stream);

    const int prep_total = n*8 + 8 + n + KK*4*COUT;
    prep<<<(prep_total + 255) / 256, 256, 0, stream>>>(
        (const float4*)feats, (const int4*)coors, weight, fh, grid, wpk, n);

    sparse_conv<<<NSLICE*2, BLOCK, 0, stream>>>((const uint4*)fh, (const int4*)coors,
                                                bias, wpk, grid, outp, n);
}

// Round 4
// 345.675 us; speedup vs baseline: 3.1838x; 3.1838x over previous
//
#include <hip/hip_runtime.h>
#include <stdint.h>

#define DD 160
#define HH 160
#define WW 160
#define NGRID (DD*HH*WW)
#define CIN 32
#define COUT 64
#define KK 27
#define BLOCK 1024
#define WPB 16           // waves per block
#define NBLOCKS 256
#define PAIR 4096        // NBLOCKS*WPB : offset between the two voxels of a pair
#define STEP 8192        // 2*PAIR : per-wave voxel stride
#define M27 0x07FFFFFFu

typedef _Float16 h2_t __attribute__((ext_vector_type(2)));

__device__ __forceinline__ h2_t as_h2(uint32_t u) {
    union { uint32_t u; h2_t h; } c; c.u = u; return c.h;
}
__device__ __forceinline__ uint32_t f2h(float f) {
    union { _Float16 h; uint16_t u; } c; c.h = (_Float16)f; return (uint32_t)c.u;
}

// 2-wide f16 dot with f32 accumulate: v_dot2_f32_f16
__device__ __forceinline__ float dot2(uint32_t fu, uint32_t wu, float acc) {
#if defined(__has_builtin)
#if __has_builtin(__builtin_amdgcn_fdot2)
    return __builtin_amdgcn_fdot2(as_h2(fu), as_h2(wu), acc, false);
#else
    h2_t f = as_h2(fu), w = as_h2(wu);
    acc = fmaf((float)f.x, (float)w.x, acc);
    return fmaf((float)f.y, (float)w.y, acc);
#endif
#else
    h2_t f = as_h2(fu), w = as_h2(wu);
    acc = fmaf((float)f.x, (float)w.x, acc);
    return fmaf((float)f.y, (float)w.y, acc);
#endif
}

// fused prep: feats f32->f16, grid scatter, weight pack f32->f16
__global__ void prep(const float4* __restrict__ f4, const int4* __restrict__ coors,
                     const float* __restrict__ w, uint2* __restrict__ fh,
                     int* __restrict__ grid, uint4* __restrict__ wpk, int n)
{
    int gid = blockIdx.x * 256 + threadIdx.x;
    const int nq = n * 8;                         // n*CIN/4 float4s == n*8 uint2 outputs
    if (gid < nq) {
        float4 v = f4[gid];
        uint2 r;
        r.x = f2h(v.x) | (f2h(v.y) << 16);
        r.y = f2h(v.z) | (f2h(v.w) << 16);
        fh[gid] = r;
    } else if (gid < nq + n) {                    // scatter voxel ids into dense grid
        int i = gid - nq;
        int4 c = coors[i];
        grid[(c.y*HH + c.z)*WW + c.w] = i;
    } else if (gid < nq + n + KK*4*COUT) {        // pack weights f32 -> f16 uint4 [k][g][co]
        int t = gid - (nq + n);
        int co = t & 63;
        int g  = (t >> 6) & 3;
        int k  = t >> 8;
        const float* base = w + (size_t)k*CIN*COUT + (size_t)(8*g)*COUT + co;
        uint4 r;
        r.x = f2h(base[0*COUT]) | (f2h(base[1*COUT]) << 16);
        r.y = f2h(base[2*COUT]) | (f2h(base[3*COUT]) << 16);
        r.z = f2h(base[4*COUT]) | (f2h(base[5*COUT]) << 16);
        r.w = f2h(base[6*COUT]) | (f2h(base[7*COUT]) << 16);
        wpk[t] = r;
    }
}

// pop next (tap k, voxel-select s) from the merged A-then-B job stream (uniform SALU)
#define POP(K,S,H) { \
    if (mlo)      { K = __ffs(mlo) - 1; mlo &= mlo - 1; S = 0; H = true; } \
    else if (mhi) { K = __ffs(mhi) - 1; mhi &= mhi - 1; S = 1; H = true; } \
    else H = false; }

// issue the 4x16B broadcast feature loads for job (K,S)
#define LOADJOB(D0,D1,D2,D3,K,S) { \
    int j_ = __builtin_amdgcn_readlane(nidx, (K) + ((S) ? 32 : 0)); \
    const uint4* fp_ = fh4 + (size_t)j_ * 4; \
    D0 = fp_[0]; D1 = fp_[1]; D2 = fp_[2]; D3 = fp_[3]; }

// 16 v_dot2_f32_f16 against LDS weights for tap kk into the given accumulator set
#define MAC4(F0,F1,F2,F3,kk,a0,a1,a2,a3) { \
    const uint4* wl_ = wlds + (size_t)(kk)*4*COUT + lane; \
    uint4 w0_ = wl_[0], w1_ = wl_[COUT], w2_ = wl_[2*COUT], w3_ = wl_[3*COUT]; \
    a0 = dot2(F0.x, w0_.x, a0); a1 = dot2(F0.y, w0_.y, a1); \
    a2 = dot2(F0.z, w0_.z, a2); a3 = dot2(F0.w, w0_.w, a3); \
    a0 = dot2(F1.x, w1_.x, a0); a1 = dot2(F1.y, w1_.y, a1); \
    a2 = dot2(F1.z, w1_.z, a2); a3 = dot2(F1.w, w1_.w, a3); \
    a0 = dot2(F2.x, w2_.x, a0); a1 = dot2(F2.y, w2_.y, a1); \
    a2 = dot2(F2.z, w2_.z, a2); a3 = dot2(F2.w, w2_.w, a3); \
    a0 = dot2(F3.x, w3_.x, a0); a1 = dot2(F3.y, w3_.y, a1); \
    a2 = dot2(F3.z, w3_.z, a2); a3 = dot2(F3.w, w3_.w, a3); }

// MAC for job (K,S): S is wave-uniform -> cheap s_cbranch between the two acc sets
#define MACJOB(F0,F1,F2,F3,K,S) { \
    if ((S) == 0) { MAC4(F0,F1,F2,F3,K,aA0,aA1,aA2,aA3) } \
    else          { MAC4(F0,F1,F2,F3,K,aB0,aB1,aB2,aB3) } }

// one wave, pair of voxels per round: lanes 0..26 probe voxel v, 32..58 probe v+PAIR.
// Merged tap stream with 3-buffer rotation = depth-2 load prefetch;
// sched_barrier(0) fences keep hipcc from re-sinking the prefetch (R2: VGPR=20 collapse).
__global__ __launch_bounds__(BLOCK, 4) void sparse_conv(
    const uint4* __restrict__ fh4, const int4* __restrict__ cc,
    const float* __restrict__ bias, const uint4* __restrict__ wpk,
    const int* __restrict__ grid, float* __restrict__ out, int n)
{
    extern __shared__ uint4 wlds[];   // [KK*4*COUT] = 110,592 B -> 1 block/CU

    for (int t = threadIdx.x; t < KK*4*COUT; t += BLOCK)
        wlds[t] = wpk[t];
    __syncthreads();

    const int lane = threadIdx.x & 63;
    const int wave = __builtin_amdgcn_readfirstlane((int)(threadIdx.x >> 6));

    const float b = bias[lane];
    const int pl = lane & 31;
    const bool prober = pl < KK;
    const int dz = pl / 9 - 1;
    const int dy = (pl / 3) % 3 - 1;
    const int dx = pl % 3 - 1;
    const int hioff = (lane >= 32) ? PAIR : 0;

    int v = blockIdx.x * WPB + wave;
    int nidx = -1;

    auto probe = [&](int pb) -> int {
        int r = -1;
        int pv = pb + hioff;
        if (prober && pv < n) {
            int4 c = cc[pv];
            int nz = c.y + dz, ny = c.z + dy, nx = c.w + dx;
            if (nz >= 0 && nz < DD && ny >= 0 && ny < HH && nx >= 0 && nx < WW)
                r = grid[(nz*HH + ny)*WW + nx];
        }
        return r;
    };

    nidx = probe(v);

    while (v < n) {
        unsigned long long bal = __ballot(nidx >= 0);
        int nidx_next = probe(v + STEP);   // next pair's probe issued early, hides under MACs

        uint32_t mlo = (uint32_t)bal & M27;           // voxel A taps (self bit 13 always set)
        uint32_t mhi = (uint32_t)(bal >> 32) & M27;   // voxel B taps

        float aA0 = 0.f, aA1 = 0.f, aA2 = 0.f, aA3 = 0.f;
        float aB0 = 0.f, aB1 = 0.f, aB2 = 0.f, aB3 = 0.f;
        uint4 P0, P1, P2, P3, Q0, Q1, Q2, Q3, R0, R1, R2, R3;
        int kP, sP, kQ, sQ, kR, sR;
        bool hP, hQ, hR;

        POP(kP, sP, hP);                       // always true (A self tap)
        LOADJOB(P0, P1, P2, P3, kP, sP);
        POP(kQ, sQ, hQ);
        if (hQ) LOADJOB(Q0, Q1, Q2, Q3, kQ, sQ);
        POP(kR, sR, hR);
        if (hR) LOADJOB(R0, R1, R2, R3, kR, sR);

        for (;;) {
            __builtin_amdgcn_sched_barrier(0);
            MACJOB(P0, P1, P2, P3, kP, sP);
            if (!hQ) break;
            POP(kP, sP, hP);
            if (hP) LOADJOB(P0, P1, P2, P3, kP, sP);
            __builtin_amdgcn_sched_barrier(0);
            MACJOB(Q0, Q1, Q2, Q3, kQ, sQ);
            if (!hR) break;
            POP(kQ, sQ, hQ);
            if (hQ) LOADJOB(Q0, Q1, Q2, Q3, kQ, sQ);
            __builtin_amdgcn_sched_barrier(0);
            MACJOB(R0, R1, R2, R3, kR, sR);
            if (!hP) break;
            POP(kR, sR, hR);
            if (hR) LOADJOB(R0, R1, R2, R3, kR, sR);
        }

        float rA = b + ((aA0 + aA1) + (aA2 + aA3));
        __builtin_nontemporal_store(rA, out + (size_t)v * COUT + lane);   // full 256B/wave
        int vB = v + PAIR;
        if (vB < n) {
            float rB = b + ((aB0 + aB1) + (aB2 + aB3));
            __builtin_nontemporal_store(rB, out + (size_t)vB * COUT + lane);
        }

        v += STEP;
        nidx = nidx_next;
    }
}

extern "C" void kernel_launch(void* const* d_in, const int* in_sizes, int n_in,
                              void* d_out, int out_size, void* d_ws, size_t ws_size,
                              hipStream_t stream) {
    const float* feats  = (const float*)d_in[0];
    const int*   coors  = (const int*)d_in[1];
    const float* weight = (const float*)d_in[2];
    const float* bias   = (const float*)d_in[3];
    float*       outp   = (float*)d_out;

    const int n = in_sizes[1] / 4;   // 400000

    int*   grid = (int*)d_ws;
    uint4* wpk  = (uint4*)((char*)d_ws + (size_t)NGRID * sizeof(int));
    uint2* fh   = (uint2*)((char*)d_ws + (size_t)NGRID * sizeof(int)
                           + (size_t)KK * 4 * COUT * sizeof(uint4));

    // dense index grid: fill with -1, then fused prep (convert + scatter + pack)
    hipMemsetAsync(grid, 0xFF, (size_t)NGRID * sizeof(int), stream);

    const int prep_total = n*8 + n + KK*4*COUT;
    prep<<<(prep_total + 255) / 256, 256, 0, stream>>>(
        (const float4*)feats, (const int4*)coors, weight, fh, grid, wpk, n);

    const size_t lds = (size_t)KK * 4 * COUT * sizeof(uint4);  // 110,592 B
    sparse_conv<<<NBLOCKS, BLOCK, lds, stream>>>((const uint4*)fh, (const int4*)coors,
                                                 bias, wpk, grid, outp, n);
}